// Round 4
// baseline (61.661 us; speedup 1.0000x reference)
//
#include <hip/hip_runtime.h>

// IntegratedColorReasoningModel: x(4096,3,64,64) fp32 -> out(4096,20) fp32
// Stage 1 (mean_lockstep): lockstep sequential-front reduction.
//   512 blocks x 1024 threads. Step k: block i reads the contiguous 16KB slab of
//   group g = k*512+i  (group = one (image,channel) 4096-float block). The whole
//   grid therefore reads ONE contiguous 8MB window per step, marching
//   sequentially through the 201MB input -> maximal DRAM row-buffer locality.
//   Each block-step produces the COMPLETE mean of group g (no cross-block
//   combine). Raw s_barrier + lgkmcnt-only waits keep the next step's preloaded
//   float4 in flight across barriers.
// Stage 2 (mlp_kernel): round-2-validated per-image MLP chain.
// Fallback: round-1-validated fused kernel.

typedef float f4 __attribute__((ext_vector_type(4)));

__device__ __forceinline__ void softmax5(const float* __restrict__ in, float* __restrict__ out) {
    float m = in[0];
#pragma unroll
    for (int i = 1; i < 5; ++i) m = fmaxf(m, in[i]);
    float e[5];
    float s = 0.f;
#pragma unroll
    for (int i = 0; i < 5; ++i) { e[i] = expf(in[i] - m); s += e[i]; }
#pragma unroll
    for (int i = 0; i < 5; ++i) out[i] = e[i] / s;
}

// ---------------------------------------------------------------------------
// Stage 1: lockstep-front channel-mean reduction.
// means[g] for g = image*3 + ch  (x is image-major, channel-contiguous).
// ---------------------------------------------------------------------------
extern "C" __global__ void __launch_bounds__(1024)
mean_lockstep(const float* __restrict__ x, float* __restrict__ means)
{
    __shared__ double part[16];
    const int tid  = threadIdx.x;
    const int lane = tid & 63;
    const int w    = tid >> 6;          // wave 0..15
    const int i    = blockIdx.x;        // 0..511

    const f4* x4 = reinterpret_cast<const f4*>(x);

    // preload step 0
    f4 v = x4[(size_t)i * 1024 + tid];

#pragma unroll
    for (int k = 0; k < 24; ++k) {
        // issue next step's load early; it stays in flight across the barriers
        f4 vn;
        if (k < 23) vn = x4[((size_t)(k + 1) * 512 + i) * 1024 + tid];

        double s = ((double)v.x + (double)v.y) + ((double)v.z + (double)v.w);
#pragma unroll
        for (int off = 32; off > 0; off >>= 1) s += __shfl_down(s, off);
        if (lane == 0) part[w] = s;

        // drain only LDS (NOT vmcnt -> vn stays outstanding), then raw barrier
        asm volatile("s_waitcnt lgkmcnt(0)" ::: "memory");
        __builtin_amdgcn_s_barrier();
        __builtin_amdgcn_sched_barrier(0);

        if (w == 0) {
            double t = (lane < 16) ? part[lane] : 0.0;
#pragma unroll
            for (int off = 8; off > 0; off >>= 1) t += __shfl_down(t, off);
            if (lane == 0) means[k * 512 + i] = (float)(t * (1.0 / 4096.0));
        }
        __builtin_amdgcn_s_barrier();
        __builtin_amdgcn_sched_barrier(0);

        v = vn;
    }
}

// ---------------------------------------------------------------------------
// Stage 2: per-image MLP chain (round-2 validated), means from d_ws.
// ---------------------------------------------------------------------------
extern "C" __global__ void __launch_bounds__(192)
mlp_kernel(const float* __restrict__ means,
           const float* __restrict__ cw1, const float* __restrict__ cb1,
           const float* __restrict__ cw2, const float* __restrict__ cb2,
           const float* __restrict__ cw3, const float* __restrict__ cb3,
           const float* __restrict__ rw1, const float* __restrict__ rb1,
           const float* __restrict__ rw2, const float* __restrict__ rb2,
           const float* __restrict__ iw1, const float* __restrict__ ib1,
           const float* __restrict__ iw2, const float* __restrict__ ib2,
           const float* __restrict__ iw3, const float* __restrict__ ib3,
           const float* __restrict__ cwgt, const float* __restrict__ rwgt,
           float* __restrict__ out)
{
    __shared__ float  s_mean[3];
    __shared__ float  s_h[128];
    __shared__ float  s_cs[64];
    __shared__ float  s_clfl[5];
    __shared__ float  s_rell[5];
    __shared__ float  s_cf[8];
    __shared__ float  s_rf[32];
    __shared__ float  s_ih[64];
    __shared__ float  s_ih2[32];
    __shared__ float  s_intl[5];
    __shared__ float  s_finl[5];
    __shared__ float  s_outp[20];

    const int tid = threadIdx.x;
    const int b   = blockIdx.x;

    if (tid < 3) s_mean[tid] = means[b * 3 + tid];
    __syncthreads();

    // B1: clf layer1 (3->128) || color bins
    if (tid < 128) {
        float a = cb1[tid]
                + s_mean[0] * cw1[tid]
                + s_mean[1] * cw1[128 + tid]
                + s_mean[2] * cw1[256 + tid];
        s_h[tid] = fmaxf(a, 0.f);
    } else if (tid == 128) {
        const float r = s_mean[0], g = s_mean[1], bl = s_mean[2];
        int idx;
        if      (r > 0.5f && g < 0.3f && bl < 0.3f) idx = 0;
        else if (r > 0.5f && g > 0.3f && bl < 0.3f) idx = 1;
        else if (r > 0.5f && g > 0.5f && bl < 0.3f) idx = 2;
        else if (r < 0.3f && g > 0.5f && bl < 0.3f) idx = 3;
        else if (r < 0.3f && g < 0.3f && bl > 0.5f) idx = 4;
        else if (r > 0.5f && g < 0.3f && bl > 0.5f) idx = 5;
        else if (r > 0.7f && g > 0.7f && bl > 0.7f) idx = 6;
        else if (r < 0.3f && g < 0.3f && bl < 0.3f) idx = 7;
        else {
            idx = 0; float m = r;
            if (g  > m) { m = g;  idx = 1; }
            if (bl > m) { m = bl; idx = 2; }
        }
#pragma unroll
        for (int j = 0; j < 8; ++j) s_cf[j] = (j == idx) ? 1.f : 0.f;
    }
    __syncthreads();

    // B2: clf layer2 (128->64) || rel layer1 (8->32)
    if (tid < 64) {
        float a = cb2[tid];
        for (int k = 0; k < 128; ++k) a += s_h[k] * cw2[k * 64 + tid];
        s_cs[tid] = fmaxf(a, 0.f);
    } else if (tid >= 64 && tid < 96) {
        const int j = tid - 64;
        float a = rb1[j];
#pragma unroll
        for (int k = 0; k < 8; ++k) a += s_cf[k] * rw1[k * 32 + j];
        s_rf[j] = fmaxf(a, 0.f);
    }
    __syncthreads();

    // B3: clf logits (64->5) || rel logits (32->5)
    if (tid < 5) {
        float a = cb3[tid];
        for (int k = 0; k < 64; ++k) a += s_cs[k] * cw3[k * 5 + tid];
        s_clfl[tid] = a;
    } else if (tid >= 32 && tid < 37) {
        const int j = tid - 32;
        float a = rb2[j];
        for (int k = 0; k < 32; ++k) a += s_rf[k] * rw2[k * 5 + j];
        s_rell[j] = a;
    }
    __syncthreads();

    // B4: softmaxes for clf & rel
    if (tid == 0)       softmax5(s_clfl, s_outp);
    else if (tid == 64) softmax5(s_rell, s_outp + 5);
    __syncthreads();

    // B5: integrator layer1 (10->64)
    if (tid < 64) {
        float a = ib1[tid];
#pragma unroll
        for (int k = 0; k < 10; ++k) a += s_outp[k] * iw1[k * 64 + tid];
        s_ih[tid] = fmaxf(a, 0.f);
    }
    __syncthreads();

    // B6: integrator layer2 (64->32) || final logits
    if (tid < 32) {
        float a = ib2[tid];
        for (int k = 0; k < 64; ++k) a += s_ih[k] * iw2[k * 32 + tid];
        s_ih2[tid] = fmaxf(a, 0.f);
    } else if (tid >= 32 && tid < 37) {
        const int j = tid - 32;
        s_finl[j] = cwgt[0] * s_clfl[j] + rwgt[0] * s_rell[j];
    }
    __syncthreads();

    // B7: integrator logits (32->5)
    if (tid < 5) {
        float a = ib3[tid];
        for (int k = 0; k < 32; ++k) a += s_ih2[k] * iw3[k * 5 + tid];
        s_intl[tid] = a;
    }
    __syncthreads();

    // B8: softmaxes for integrated & final
    if (tid == 0)       softmax5(s_intl, s_outp + 10);
    else if (tid == 64) softmax5(s_finl, s_outp + 15);
    __syncthreads();

    if (tid < 20) out[(size_t)b * 20 + tid] = s_outp[tid];
}

// ---------------------------------------------------------------------------
// Fallback: round-1 validated fused kernel (ws too small OR unexpected shape).
// ---------------------------------------------------------------------------
extern "C" __global__ void __launch_bounds__(256)
icrm_fused(const float* __restrict__ x,
           const float* __restrict__ cw1, const float* __restrict__ cb1,
           const float* __restrict__ cw2, const float* __restrict__ cb2,
           const float* __restrict__ cw3, const float* __restrict__ cb3,
           const float* __restrict__ rw1, const float* __restrict__ rb1,
           const float* __restrict__ rw2, const float* __restrict__ rb2,
           const float* __restrict__ iw1, const float* __restrict__ ib1,
           const float* __restrict__ iw2, const float* __restrict__ ib2,
           const float* __restrict__ iw3, const float* __restrict__ ib3,
           const float* __restrict__ cwgt, const float* __restrict__ rwgt,
           float* __restrict__ out)
{
    __shared__ float  s_mean[3];
    __shared__ float  s_h[128];
    __shared__ float  s_cs[64];
    __shared__ float  s_clfl[5];
    __shared__ float  s_rell[5];
    __shared__ float  s_cf[8];
    __shared__ float  s_rf[32];
    __shared__ float  s_ih[64];
    __shared__ float  s_ih2[32];
    __shared__ float  s_intl[5];
    __shared__ float  s_finl[5];
    __shared__ float  s_outp[20];
    __shared__ double s_wsum[3][4];

    const int tid = threadIdx.x;
    const int b   = blockIdx.x;

    const float4* xb = reinterpret_cast<const float4*>(x + (size_t)b * 12288);
    double s0 = 0.0, s1 = 0.0, s2 = 0.0;
#pragma unroll
    for (int k = 0; k < 4; ++k) {
        float4 v0 = xb[tid + k * 256];
        float4 v1 = xb[1024 + tid + k * 256];
        float4 v2 = xb[2048 + tid + k * 256];
        s0 += (double)v0.x + (double)v0.y + (double)v0.z + (double)v0.w;
        s1 += (double)v1.x + (double)v1.y + (double)v1.z + (double)v1.w;
        s2 += (double)v2.x + (double)v2.y + (double)v2.z + (double)v2.w;
    }
#pragma unroll
    for (int off = 32; off > 0; off >>= 1) {
        s0 += __shfl_down(s0, off);
        s1 += __shfl_down(s1, off);
        s2 += __shfl_down(s2, off);
    }
    const int wid = tid >> 6;
    if ((tid & 63) == 0) { s_wsum[0][wid] = s0; s_wsum[1][wid] = s1; s_wsum[2][wid] = s2; }
    __syncthreads();
    if (tid < 3) {
        double t = (s_wsum[tid][0] + s_wsum[tid][1]) + (s_wsum[tid][2] + s_wsum[tid][3]);
        s_mean[tid] = (float)(t * (1.0 / 4096.0));
    }
    __syncthreads();

    if (tid < 128) {
        float a = cb1[tid]
                + s_mean[0] * cw1[tid]
                + s_mean[1] * cw1[128 + tid]
                + s_mean[2] * cw1[256 + tid];
        s_h[tid] = fmaxf(a, 0.f);
    } else if (tid == 128) {
        const float r = s_mean[0], g = s_mean[1], bl = s_mean[2];
        int idx;
        if      (r > 0.5f && g < 0.3f && bl < 0.3f) idx = 0;
        else if (r > 0.5f && g > 0.3f && bl < 0.3f) idx = 1;
        else if (r > 0.5f && g > 0.5f && bl < 0.3f) idx = 2;
        else if (r < 0.3f && g > 0.5f && bl < 0.3f) idx = 3;
        else if (r < 0.3f && g < 0.3f && bl > 0.5f) idx = 4;
        else if (r > 0.5f && g < 0.3f && bl > 0.5f) idx = 5;
        else if (r > 0.7f && g > 0.7f && bl > 0.7f) idx = 6;
        else if (r < 0.3f && g < 0.3f && bl < 0.3f) idx = 7;
        else {
            idx = 0; float m = r;
            if (g  > m) { m = g;  idx = 1; }
            if (bl > m) { m = bl; idx = 2; }
        }
#pragma unroll
        for (int j = 0; j < 8; ++j) s_cf[j] = (j == idx) ? 1.f : 0.f;
    }
    __syncthreads();

    if (tid < 64) {
        float a = cb2[tid];
        for (int k = 0; k < 128; ++k) a += s_h[k] * cw2[k * 64 + tid];
        s_cs[tid] = fmaxf(a, 0.f);
    } else if (tid >= 64 && tid < 96) {
        const int j = tid - 64;
        float a = rb1[j];
#pragma unroll
        for (int k = 0; k < 8; ++k) a += s_cf[k] * rw1[k * 32 + j];
        s_rf[j] = fmaxf(a, 0.f);
    }
    __syncthreads();

    if (tid < 5) {
        float a = cb3[tid];
        for (int k = 0; k < 64; ++k) a += s_cs[k] * cw3[k * 5 + tid];
        s_clfl[tid] = a;
    } else if (tid >= 32 && tid < 37) {
        const int j = tid - 32;
        float a = rb2[j];
        for (int k = 0; k < 32; ++k) a += s_rf[k] * rw2[k * 5 + j];
        s_rell[j] = a;
    }
    __syncthreads();

    if (tid == 0)       softmax5(s_clfl, s_outp);
    else if (tid == 64) softmax5(s_rell, s_outp + 5);
    __syncthreads();

    if (tid < 64) {
        float a = ib1[tid];
#pragma unroll
        for (int k = 0; k < 10; ++k) a += s_outp[k] * iw1[k * 64 + tid];
        s_ih[tid] = fmaxf(a, 0.f);
    }
    __syncthreads();

    if (tid < 32) {
        float a = ib2[tid];
        for (int k = 0; k < 64; ++k) a += s_ih[k] * iw2[k * 32 + tid];
        s_ih2[tid] = fmaxf(a, 0.f);
    } else if (tid >= 32 && tid < 37) {
        const int j = tid - 32;
        s_finl[j] = cwgt[0] * s_clfl[j] + rwgt[0] * s_rell[j];
    }
    __syncthreads();

    if (tid < 5) {
        float a = ib3[tid];
        for (int k = 0; k < 32; ++k) a += s_ih2[k] * iw3[k * 5 + tid];
        s_intl[tid] = a;
    }
    __syncthreads();

    if (tid == 0)       softmax5(s_intl, s_outp + 10);
    else if (tid == 64) softmax5(s_finl, s_outp + 15);
    __syncthreads();

    if (tid < 20) out[(size_t)b * 20 + tid] = s_outp[tid];
}

extern "C" void kernel_launch(void* const* d_in, const int* in_sizes, int n_in,
                              void* d_out, int out_size, void* d_ws, size_t ws_size,
                              hipStream_t stream) {
    const float* x    = (const float*)d_in[0];
    const float* cw1  = (const float*)d_in[1];
    const float* cb1  = (const float*)d_in[2];
    const float* cw2  = (const float*)d_in[3];
    const float* cb2  = (const float*)d_in[4];
    const float* cw3  = (const float*)d_in[5];
    const float* cb3  = (const float*)d_in[6];
    const float* rw1  = (const float*)d_in[7];
    const float* rb1  = (const float*)d_in[8];
    const float* rw2  = (const float*)d_in[9];
    const float* rb2  = (const float*)d_in[10];
    const float* iw1  = (const float*)d_in[11];
    const float* ib1  = (const float*)d_in[12];
    const float* iw2  = (const float*)d_in[13];
    const float* ib2  = (const float*)d_in[14];
    const float* iw3  = (const float*)d_in[15];
    const float* ib3  = (const float*)d_in[16];
    const float* cwgt = (const float*)d_in[17];
    const float* rwgt = (const float*)d_in[18];
    float* out = (float*)d_out;

    const int B = in_sizes[0] / (3 * 64 * 64);   // 4096

    // mean_lockstep geometry is hardcoded for B=4096 (512 blocks x 24 steps)
    if (B == 4096 && ws_size >= (size_t)B * 3 * sizeof(float)) {
        float* means = (float*)d_ws;
        mean_lockstep<<<512, 1024, 0, stream>>>(x, means);
        mlp_kernel<<<B, 192, 0, stream>>>(means, cw1, cb1, cw2, cb2, cw3, cb3,
                                          rw1, rb1, rw2, rb2,
                                          iw1, ib1, iw2, ib2, iw3, ib3,
                                          cwgt, rwgt, out);
    } else {
        icrm_fused<<<B, 256, 0, stream>>>(x, cw1, cb1, cw2, cb2, cw3, cb3,
                                          rw1, rb1, rw2, rb2,
                                          iw1, ib1, iw2, ib2, iw3, ib3,
                                          cwgt, rwgt, out);
    }
}

// Round 5
// 47.815 us; speedup vs baseline: 1.2896x; 1.2896x over previous
//
#include <hip/hip_runtime.h>

// IntegratedColorReasoningModel: x(4096,3,64,64) fp32 -> out(4096,20) fp32
// Round-1 validated fused kernel (best measured: 47.97 us, absmax 0.0).
// One block per image. Phase A: channel means (fp64 accum, coalesced float4).
// Phase B: tiny MLP chain staged through LDS.
//
// Measured evidence (rounds 1-4): the streaming phase is pinned at ~4.28 TB/s
// (16.7 GB/s/CU) across register-staged, direct-to-LDS, and lockstep-front
// structures -> per-CU read-tracking hardware cap; this kernel is ~2.5% off
// the floor implied by that cap.

__device__ __forceinline__ void softmax5(const float* __restrict__ in, float* __restrict__ out) {
    float m = in[0];
#pragma unroll
    for (int i = 1; i < 5; ++i) m = fmaxf(m, in[i]);
    float e[5];
    float s = 0.f;
#pragma unroll
    for (int i = 0; i < 5; ++i) { e[i] = expf(in[i] - m); s += e[i]; }
#pragma unroll
    for (int i = 0; i < 5; ++i) out[i] = e[i] / s;
}

extern "C" __global__ void __launch_bounds__(256)
icrm_kernel(const float* __restrict__ x,
            const float* __restrict__ cw1, const float* __restrict__ cb1,
            const float* __restrict__ cw2, const float* __restrict__ cb2,
            const float* __restrict__ cw3, const float* __restrict__ cb3,
            const float* __restrict__ rw1, const float* __restrict__ rb1,
            const float* __restrict__ rw2, const float* __restrict__ rb2,
            const float* __restrict__ iw1, const float* __restrict__ ib1,
            const float* __restrict__ iw2, const float* __restrict__ ib2,
            const float* __restrict__ iw3, const float* __restrict__ ib3,
            const float* __restrict__ cwgt, const float* __restrict__ rwgt,
            float* __restrict__ out)
{
    __shared__ float  s_mean[3];
    __shared__ float  s_h[128];
    __shared__ float  s_cs[64];
    __shared__ float  s_clfl[5];
    __shared__ float  s_rell[5];
    __shared__ float  s_cf[8];
    __shared__ float  s_rf[32];
    __shared__ float  s_ih[64];
    __shared__ float  s_ih2[32];
    __shared__ float  s_intl[5];
    __shared__ float  s_finl[5];
    __shared__ float  s_outp[20];   // [0:5) clf_probs, [5:10) rel_probs, [10:15) int_probs, [15:20) final_probs
    __shared__ double s_wsum[3][4];

    const int tid = threadIdx.x;
    const int b   = blockIdx.x;

    // ---------------- Phase A: per-channel mean over 64*64 = 4096 elements -----------
    // Each channel plane is 4096 contiguous floats = 1024 float4.
    const float4* xb = reinterpret_cast<const float4*>(x + (size_t)b * 12288);
    double s0 = 0.0, s1 = 0.0, s2 = 0.0;
#pragma unroll
    for (int k = 0; k < 4; ++k) {
        float4 v0 = xb[tid + k * 256];
        float4 v1 = xb[1024 + tid + k * 256];
        float4 v2 = xb[2048 + tid + k * 256];
        s0 += (double)v0.x + (double)v0.y + (double)v0.z + (double)v0.w;
        s1 += (double)v1.x + (double)v1.y + (double)v1.z + (double)v1.w;
        s2 += (double)v2.x + (double)v2.y + (double)v2.z + (double)v2.w;
    }
    // wave(64)-level reduce
#pragma unroll
    for (int off = 32; off > 0; off >>= 1) {
        s0 += __shfl_down(s0, off);
        s1 += __shfl_down(s1, off);
        s2 += __shfl_down(s2, off);
    }
    const int wid = tid >> 6;
    if ((tid & 63) == 0) { s_wsum[0][wid] = s0; s_wsum[1][wid] = s1; s_wsum[2][wid] = s2; }
    __syncthreads();
    if (tid < 3) {
        double t = (s_wsum[tid][0] + s_wsum[tid][1]) + (s_wsum[tid][2] + s_wsum[tid][3]);
        s_mean[tid] = (float)(t * (1.0 / 4096.0));
    }
    __syncthreads();

    // ---------------- Phase B1: clf layer1 (3->128) || color bins ----------------
    if (tid < 128) {
        float a = cb1[tid]
                + s_mean[0] * cw1[tid]
                + s_mean[1] * cw1[128 + tid]
                + s_mean[2] * cw1[256 + tid];
        s_h[tid] = fmaxf(a, 0.f);
    } else if (tid == 128) {
        const float r = s_mean[0], g = s_mean[1], bl = s_mean[2];
        int idx;
        if      (r > 0.5f && g < 0.3f && bl < 0.3f) idx = 0;
        else if (r > 0.5f && g > 0.3f && bl < 0.3f) idx = 1;
        else if (r > 0.5f && g > 0.5f && bl < 0.3f) idx = 2;
        else if (r < 0.3f && g > 0.5f && bl < 0.3f) idx = 3;
        else if (r < 0.3f && g < 0.3f && bl > 0.5f) idx = 4;
        else if (r > 0.5f && g < 0.3f && bl > 0.5f) idx = 5;
        else if (r > 0.7f && g > 0.7f && bl > 0.7f) idx = 6;
        else if (r < 0.3f && g < 0.3f && bl < 0.3f) idx = 7;
        else { // fallback: argmax(mean_rgb), first index on ties
            idx = 0; float m = r;
            if (g  > m) { m = g;  idx = 1; }
            if (bl > m) { m = bl; idx = 2; }
        }
#pragma unroll
        for (int j = 0; j < 8; ++j) s_cf[j] = (j == idx) ? 1.f : 0.f;
    }
    __syncthreads();

    // ---------------- Phase B2: clf layer2 (128->64) || rel layer1 (8->32) --------
    if (tid < 64) {
        float a = cb2[tid];
        for (int k = 0; k < 128; ++k) a += s_h[k] * cw2[k * 64 + tid];
        s_cs[tid] = fmaxf(a, 0.f);
    } else if (tid >= 64 && tid < 96) {
        const int j = tid - 64;
        float a = rb1[j];
#pragma unroll
        for (int k = 0; k < 8; ++k) a += s_cf[k] * rw1[k * 32 + j];
        s_rf[j] = fmaxf(a, 0.f);
    }
    __syncthreads();

    // ---------------- Phase B3: clf logits (64->5) || rel logits (32->5) ----------
    if (tid < 5) {
        float a = cb3[tid];
        for (int k = 0; k < 64; ++k) a += s_cs[k] * cw3[k * 5 + tid];
        s_clfl[tid] = a;
    } else if (tid >= 32 && tid < 37) {
        const int j = tid - 32;
        float a = rb2[j];
        for (int k = 0; k < 32; ++k) a += s_rf[k] * rw2[k * 5 + j];
        s_rell[j] = a;
    }
    __syncthreads();

    // ---------------- Phase B4: softmaxes for clf & rel ---------------------------
    if (tid == 0)       softmax5(s_clfl, s_outp);        // clf_probs  -> outp[0..4]
    else if (tid == 64) softmax5(s_rell, s_outp + 5);    // rel_probs  -> outp[5..9]
    __syncthreads();

    // ---------------- Phase B5: integrator layer1 (10->64) ------------------------
    if (tid < 64) {
        float a = ib1[tid];
#pragma unroll
        for (int k = 0; k < 10; ++k) a += s_outp[k] * iw1[k * 64 + tid];
        s_ih[tid] = fmaxf(a, 0.f);
    }
    __syncthreads();

    // ---------------- Phase B6: integrator layer2 (64->32) || final logits --------
    if (tid < 32) {
        float a = ib2[tid];
        for (int k = 0; k < 64; ++k) a += s_ih[k] * iw2[k * 32 + tid];
        s_ih2[tid] = fmaxf(a, 0.f);
    } else if (tid >= 32 && tid < 37) {
        const int j = tid - 32;
        s_finl[j] = cwgt[0] * s_clfl[j] + rwgt[0] * s_rell[j];
    }
    __syncthreads();

    // ---------------- Phase B7: integrator logits (32->5) -------------------------
    if (tid < 5) {
        float a = ib3[tid];
        for (int k = 0; k < 32; ++k) a += s_ih2[k] * iw3[k * 5 + tid];
        s_intl[tid] = a;
    }
    __syncthreads();

    // ---------------- Phase B8: softmaxes for integrated & final ------------------
    if (tid == 0)       softmax5(s_intl, s_outp + 10);   // int_probs   -> outp[10..14]
    else if (tid == 64) softmax5(s_finl, s_outp + 15);   // final_probs -> outp[15..19]
    __syncthreads();

    // ---------------- Output write -------------------------------------------------
    if (tid < 20) out[(size_t)b * 20 + tid] = s_outp[tid];
}

extern "C" void kernel_launch(void* const* d_in, const int* in_sizes, int n_in,
                              void* d_out, int out_size, void* d_ws, size_t ws_size,
                              hipStream_t stream) {
    const float* x    = (const float*)d_in[0];
    const float* cw1  = (const float*)d_in[1];
    const float* cb1  = (const float*)d_in[2];
    const float* cw2  = (const float*)d_in[3];
    const float* cb2  = (const float*)d_in[4];
    const float* cw3  = (const float*)d_in[5];
    const float* cb3  = (const float*)d_in[6];
    const float* rw1  = (const float*)d_in[7];
    const float* rb1  = (const float*)d_in[8];
    const float* rw2  = (const float*)d_in[9];
    const float* rb2  = (const float*)d_in[10];
    const float* iw1  = (const float*)d_in[11];
    const float* ib1  = (const float*)d_in[12];
    const float* iw2  = (const float*)d_in[13];
    const float* ib2  = (const float*)d_in[14];
    const float* iw3  = (const float*)d_in[15];
    const float* ib3  = (const float*)d_in[16];
    const float* cwgt = (const float*)d_in[17];
    const float* rwgt = (const float*)d_in[18];
    float* out = (float*)d_out;

    const int B = in_sizes[0] / (3 * 64 * 64);   // 4096
    icrm_kernel<<<B, 256, 0, stream>>>(x, cw1, cb1, cw2, cb2, cw3, cb3,
                                       rw1, rb1, rw2, rb2,
                                       iw1, ib1, iw2, ib2, iw3, ib3,
                                       cwgt, rwgt, out);
}